// Round 14
// baseline (32.762 us; speedup 1.0000x reference)
//
#include <hip/hip_runtime.h>

#define B_   4
#define L_   1024
#define D_   16
#define H_   32
#define TAU_ 64
#define EMB_ 8
#define AEP_ 34   // ae_lds stride: even -> 8B-aligned f2 reads, 2-way banks (free)
#define TI_  32   // i-tile height
#define JT_  128  // j-tile width: TWO 64-wide subtiles per wave (row-read amortized 2x)

typedef float f2 __attribute__((ext_vector_type(2)));

// ---------------------------------------------------------------------------
// Kernel 1: precompute (R9 verbatim)
//   ai[b,l,h] = x[b,l,:] @ W1[0:16, h]
//   aj[b,l,h] = x[b,l,:] @ W1[16:32, h]
//   ae[t,h]   = dt_table[t,:] @ W1[32:40, h] + b1[h]
// ---------------------------------------------------------------------------
__global__ __launch_bounds__(256) void precompute_kernel(
    const float* __restrict__ x, const float* __restrict__ dtt,
    const float* __restrict__ W1, const float* __restrict__ b1,
    float* __restrict__ ai, float* __restrict__ aj, float* __restrict__ ae)
{
    const int id = blockIdx.x * 256 + threadIdx.x;
    const int NA = B_ * L_ * H_;
    if (id < NA) {
        const int h   = id & (H_ - 1);
        const int row = id >> 5;                 // b*L + l
        const float4* xr4 = (const float4*)(x + row * D_);
        const float4 v0 = xr4[0], v1 = xr4[1], v2 = xr4[2], v3 = xr4[3];
        const float xv[D_] = {v0.x, v0.y, v0.z, v0.w, v1.x, v1.y, v1.z, v1.w,
                              v2.x, v2.y, v2.z, v2.w, v3.x, v3.y, v3.z, v3.w};
        float s1 = 0.f, s2 = 0.f;
#pragma unroll
        for (int d = 0; d < D_; ++d) {
            s1 = fmaf(xv[d], W1[d * H_ + h], s1);
            s2 = fmaf(xv[d], W1[(D_ + d) * H_ + h], s2);
        }
        ai[id] = s1;
        aj[id] = s2;
    } else {
        const int k = id - NA;
        if (k < (TAU_ + 1) * H_) {
            const int h = k & (H_ - 1);
            const int t = k >> 5;
            float s = b1[h];
#pragma unroll
            for (int e = 0; e < EMB_; ++e)
                s = fmaf(dtt[t * EMB_ + e], W1[(2 * D_ + e) * H_ + h], s);
            ae[k] = s;
        }
    }
}

// ---------------------------------------------------------------------------
// Kernel 2: bias kernel, 2-j-subtile edition.
// R13 analysis: bias ~16.8us, bound by LDS row-read traffic (8 ds_read_b128
// per 64 outputs, ~12cyc each on the per-CU LDS pipe ~= 10us) -- not VALU
// (2.6us), not occupancy, not SMEM-vs-LDS. Fix: each wave covers TWO 64-wide
// j-subtiles (j0+lane, j0+64+lane); one row read now feeds 128 outputs.
// All global access patterns identical to R13 (per-lane float4 aj reads of
// consecutive rows; NT dword wave-stores) -- avoids R12's fetch explosion.
// Tile 32i x 128j -> grid 1024 (4 blocks/CU; R9 showed 50% occ costs <=3%).
// ---------------------------------------------------------------------------
__global__ __launch_bounds__(256) void bias_kernel(
    const float* __restrict__ ai, const float* __restrict__ aj,
    const float* __restrict__ ae, const float* __restrict__ W2,
    const float* __restrict__ b2p, float* __restrict__ out)
{
    __shared__ float ai_lds[TI_ * H_];            // 4 KB: this block's ai tile
    __shared__ float ae_lds[(TAU_ + 1) * AEP_];   // 8.8 KB: band blocks only

    const int b    = blockIdx.z;
    const int i0   = blockIdx.y * TI_;
    const int j0   = blockIdx.x * JT_;
    const int tid  = threadIdx.x;
    const int lane = tid & 63;
    const int w    = __builtin_amdgcn_readfirstlane(tid >> 6);
    const int ja   = j0 + lane;          // first j-subtile column
    // second subtile column = ja + 64

    const bool c0  = (j0 >= i0 + TI_);            // dt==0 over whole tile
    const bool c64 = (i0 >= j0 + JT_ + TAU_);     // dt==64 over whole tile
    const bool constpath = c0 || c64;

    const float b2 = *b2p;

    // ---- Stage ai tile: 32 rows x 32 h = 1024 floats = 256 float4. ----
    {
        const float4* src = (const float4*)(ai + ((size_t)(b * L_ + i0)) * H_);
        ((float4*)ai_lds)[tid] = src[tid];
    }

    // Per-lane column vectors for the two owned j's (R13 access pattern x2).
    f2 r2a[H_ / 2], r2b[H_ / 2];
    {
        const float* ajrA = aj + ((size_t)(b * L_ + ja)) * H_;
        const float* ajrB = ajrA + 64 * H_;
#pragma unroll
        for (int h = 0; h < H_; h += 4) {
            const float4 va = *(const float4*)(ajrA + h);
            const float4 vb = *(const float4*)(ajrB + h);
            r2a[(h >> 1) + 0] = (f2){va.x, va.y};
            r2a[(h >> 1) + 1] = (f2){va.z, va.w};
            r2b[(h >> 1) + 0] = (f2){vb.x, vb.y};
            r2b[(h >> 1) + 1] = (f2){vb.z, vb.w};
        }
    }

    if (constpath) {
        const float* aec = ae + (c0 ? 0 : TAU_) * H_;   // uniform -> s_load once
#pragma unroll
        for (int h = 0; h < H_; h += 2) {
            const f2 e = {aec[h], aec[h + 1]};
            r2a[h >> 1] += e;
            r2b[h >> 1] += e;
        }
    } else {
        for (int k = tid; k < (TAU_ + 1) * H_; k += 256)
            ae_lds[(k >> 5) * AEP_ + (k & 31)] = ae[k];
    }
    __syncthreads();   // covers ai_lds (all paths) + ae_lds (band)

    const float* aiW = &ai_lds[(w * 8) * H_];   // wave's 8 rows in LDS
    float* outb = out + ((size_t)b) * L_ * L_ + ((size_t)(i0 + w * 8)) * L_ + ja;
    const f2 z2 = {0.f, 0.f};

    if (constpath) {
        const float pc = b2 - 0.2f * (c0 ? 0.f : (float)TAU_);
        for (int ii = 0; ii < 8; ++ii) {
            const float4* ar = (const float4*)&aiW[ii * H_];   // uniform bcast
            f2 accA = z2, accB = z2;
#pragma unroll
            for (int q = 0; q < 8; ++q) {
                const float4 qa = ar[q];        // ds_read_b128, feeds BOTH j-sets
                const int h = q * 4;
                const f2 wv0 = {W2[h], W2[h + 1]};
                const f2 wv1 = {W2[h + 2], W2[h + 3]};
                const f2 a0 = {qa.x, qa.y};
                const f2 a1 = {qa.z, qa.w};
                f2 pA0 = a0 + r2a[(h >> 1) + 0];
                f2 pA1 = a1 + r2a[(h >> 1) + 1];
                f2 pB0 = a0 + r2b[(h >> 1) + 0];
                f2 pB1 = a1 + r2b[(h >> 1) + 1];
                pA0 = __builtin_elementwise_max(pA0, z2);
                pA1 = __builtin_elementwise_max(pA1, z2);
                pB0 = __builtin_elementwise_max(pB0, z2);
                pB1 = __builtin_elementwise_max(pB1, z2);
                accA = __builtin_elementwise_fma(pA0, wv0, accA);
                accA = __builtin_elementwise_fma(pA1, wv1, accA);
                accB = __builtin_elementwise_fma(pB0, wv0, accB);
                accB = __builtin_elementwise_fma(pB1, wv1, accB);
            }
            float* o = outb + (size_t)ii * L_;
            __builtin_nontemporal_store(accA.x + accA.y + pc, o);
            __builtin_nontemporal_store(accB.x + accB.y + pc, o + 64);
        }
    } else {
        for (int ii = 0; ii < 8; ++ii) {
            const int i   = i0 + w * 8 + ii;
            const int dA  = i - ja;
            const int dB  = dA - 64;
            const int dtA = dA < 0 ? 0 : (dA > TAU_ ? TAU_ : dA);
            const int dtB = dB < 0 ? 0 : (dB > TAU_ ? TAU_ : dB);
            const f2* eA  = (const f2*)&ae_lds[dtA * AEP_];   // 8B aligned
            const f2* eB  = (const f2*)&ae_lds[dtB * AEP_];
            const float4* ar = (const float4*)&aiW[ii * H_];
            f2 accA = z2, accB = z2;
#pragma unroll
            for (int q = 0; q < 8; ++q) {
                const float4 qa = ar[q];
                const int h = q * 4;
                const f2 wv0 = {W2[h], W2[h + 1]};
                const f2 wv1 = {W2[h + 2], W2[h + 3]};
                const f2 a0 = {qa.x, qa.y};
                const f2 a1 = {qa.z, qa.w};
                f2 pA0 = a0 + r2a[(h >> 1) + 0] + eA[(h >> 1) + 0];
                f2 pA1 = a1 + r2a[(h >> 1) + 1] + eA[(h >> 1) + 1];
                f2 pB0 = a0 + r2b[(h >> 1) + 0] + eB[(h >> 1) + 0];
                f2 pB1 = a1 + r2b[(h >> 1) + 1] + eB[(h >> 1) + 1];
                pA0 = __builtin_elementwise_max(pA0, z2);
                pA1 = __builtin_elementwise_max(pA1, z2);
                pB0 = __builtin_elementwise_max(pB0, z2);
                pB1 = __builtin_elementwise_max(pB1, z2);
                accA = __builtin_elementwise_fma(pA0, wv0, accA);
                accA = __builtin_elementwise_fma(pA1, wv1, accA);
                accB = __builtin_elementwise_fma(pB0, wv0, accB);
                accB = __builtin_elementwise_fma(pB1, wv1, accB);
            }
            float* o = outb + (size_t)ii * L_;
            __builtin_nontemporal_store(accA.x + accA.y + b2 - 0.2f * (float)dtA, o);
            __builtin_nontemporal_store(accB.x + accB.y + b2 - 0.2f * (float)dtB, o + 64);
        }
    }
}

extern "C" void kernel_launch(void* const* d_in, const int* in_sizes, int n_in,
                              void* d_out, int out_size, void* d_ws, size_t ws_size,
                              hipStream_t stream) {
    const float* x   = (const float*)d_in[0];
    const float* dtt = (const float*)d_in[1];
    const float* W1  = (const float*)d_in[2];
    const float* b1  = (const float*)d_in[3];
    const float* W2  = (const float*)d_in[4];
    const float* b2  = (const float*)d_in[5];
    float* out = (float*)d_out;

    float* ws = (float*)d_ws;
    float* ai = ws;                          // B*L*H floats
    float* aj = ws + B_ * L_ * H_;           // B*L*H floats
    float* ae = ws + 2 * B_ * L_ * H_;       // 65*H floats

    const int total  = B_ * L_ * H_ + (TAU_ + 1) * H_;
    const int blocks = (total + 255) / 256;
    hipLaunchKernelGGL(precompute_kernel, dim3(blocks), dim3(256), 0, stream,
                       x, dtt, W1, b1, ai, aj, ae);

    dim3 grid(L_ / JT_, L_ / TI_, B_);
    hipLaunchKernelGGL(bias_kernel, grid, dim3(256), 0, stream,
                       ai, aj, ae, W2, b2, out);
}

// Round 15
// 28.488 us; speedup vs baseline: 1.1500x; 1.1500x over previous
//
#include <hip/hip_runtime.h>

#define B_   4
#define L_   1024
#define D_   16
#define H_   32
#define TAU_ 64
#define EMB_ 8
#define AEP_ 34   // ae_lds stride: even -> 8B-aligned f2 reads, 2-way banks (free)
#define TI_  32   // i-tile height: 2048 blocks = 8 blocks/CU -> 100% occupancy

typedef float f2 __attribute__((ext_vector_type(2)));

// ---------------------------------------------------------------------------
// Kernel 1: precompute (R9 verbatim)
//   ai[b,l,h] = x[b,l,:] @ W1[0:16, h]
//   aj[b,l,h] = x[b,l,:] @ W1[16:32, h]
//   ae[t,h]   = dt_table[t,:] @ W1[32:40, h] + b1[h]
// ---------------------------------------------------------------------------
__global__ __launch_bounds__(256) void precompute_kernel(
    const float* __restrict__ x, const float* __restrict__ dtt,
    const float* __restrict__ W1, const float* __restrict__ b1,
    float* __restrict__ ai, float* __restrict__ aj, float* __restrict__ ae)
{
    const int id = blockIdx.x * 256 + threadIdx.x;
    const int NA = B_ * L_ * H_;
    if (id < NA) {
        const int h   = id & (H_ - 1);
        const int row = id >> 5;                 // b*L + l
        const float4* xr4 = (const float4*)(x + row * D_);
        const float4 v0 = xr4[0], v1 = xr4[1], v2 = xr4[2], v3 = xr4[3];
        const float xv[D_] = {v0.x, v0.y, v0.z, v0.w, v1.x, v1.y, v1.z, v1.w,
                              v2.x, v2.y, v2.z, v2.w, v3.x, v3.y, v3.z, v3.w};
        float s1 = 0.f, s2 = 0.f;
#pragma unroll
        for (int d = 0; d < D_; ++d) {
            s1 = fmaf(xv[d], W1[d * H_ + h], s1);
            s2 = fmaf(xv[d], W1[(D_ + d) * H_ + h], s2);
        }
        ai[id] = s1;
        aj[id] = s2;
    } else {
        const int k = id - NA;
        if (k < (TAU_ + 1) * H_) {
            const int h = k & (H_ - 1);
            const int t = k >> 5;
            float s = b1[h];
#pragma unroll
            for (int e = 0; e < EMB_; ++e)
                s = fmaf(dtt[t * EMB_ + e], W1[(2 * D_ + e) * H_ + h], s);
            ae[k] = s;
        }
    }
}

// ---------------------------------------------------------------------------
// Kernel 2: bias kernel, plain-store edition (R13 + ONE change).
// R12's counters revealed WRITE_SIZE 183MB / FETCH 112MB vs a 16.8MB output
// model: NT stores (L2-bypass) appear not to write-combine -> RMW
// amplification at HBM. All fast variants so far used NT dword stores.
// Single-variable test: identical to R13 except plain stores (L2 write-back;
// lines fully covered by the wave's contiguous 256B; drain off critical path).
// ---------------------------------------------------------------------------
__global__ __launch_bounds__(256, 8) void bias_kernel(
    const float* __restrict__ ai, const float* __restrict__ aj,
    const float* __restrict__ ae, const float* __restrict__ W2,
    const float* __restrict__ b2p, float* __restrict__ out)
{
    __shared__ float ai_lds[TI_ * H_];            // 4 KB: this block's ai tile
    __shared__ float ae_lds[(TAU_ + 1) * AEP_];   // 8.8 KB: band blocks only

    const int b    = blockIdx.z;
    const int i0   = blockIdx.y * TI_;
    const int j0   = blockIdx.x * 64;
    const int tid  = threadIdx.x;
    const int lane = tid & 63;
    const int w    = __builtin_amdgcn_readfirstlane(tid >> 6);
    const int j    = j0 + lane;

    const bool c0  = (j0 >= i0 + TI_);     // dt==0 over whole tile
    const bool c64 = (i0 >= j0 + 128);     // dt==64 over whole tile
    const bool constpath = c0 || c64;

    const float b2 = *b2p;

    // ---- Stage ai tile: 32 rows x 32 h = 1024 floats = 256 float4. ----
    {
        const float4* src = (const float4*)(ai + ((size_t)(b * L_ + i0)) * H_);
        ((float4*)ai_lds)[tid] = src[tid];
    }

    // Per-lane column vector r2[h/2] = aj[j, h..h+1] (+ ae row on const path).
    f2 r2[H_ / 2];
    {
        const float* ajr = aj + ((size_t)(b * L_ + j)) * H_;
#pragma unroll
        for (int h = 0; h < H_; h += 4) {
            const float4 v = *(const float4*)(ajr + h);
            r2[(h >> 1) + 0] = (f2){v.x, v.y};
            r2[(h >> 1) + 1] = (f2){v.z, v.w};
        }
    }

    if (constpath) {
        const float* aec = ae + (c0 ? 0 : TAU_) * H_;   // uniform -> s_load, once
#pragma unroll
        for (int h = 0; h < H_; h += 2) {
            const f2 e = {aec[h], aec[h + 1]};
            r2[h >> 1] += e;
        }
    } else {
        for (int k = tid; k < (TAU_ + 1) * H_; k += 256)
            ae_lds[(k >> 5) * AEP_ + (k & 31)] = ae[k];
    }
    __syncthreads();   // covers ai_lds (all paths) + ae_lds (band)

    const float* aiW = &ai_lds[(w * 8) * H_];   // wave's 8 rows in LDS
    float* outb = out + ((size_t)b) * L_ * L_ + ((size_t)(i0 + w * 8)) * L_ + j;
    const f2 z2 = {0.f, 0.f};

    if (constpath) {
        const float pc = b2 - 0.2f * (c0 ? 0.f : (float)TAU_);
        for (int ii = 0; ii < 8; ii += 2) {
            const float4* ar0 = (const float4*)&aiW[(ii + 0) * H_];  // uniform
            const float4* ar1 = (const float4*)&aiW[(ii + 1) * H_];  // broadcast
            f2 acc0 = z2, acc1 = z2;
#pragma unroll
            for (int q = 0; q < 8; ++q) {
                const float4 q0 = ar0[q];       // ds_read_b128, pipelined
                const float4 q1 = ar1[q];
                const int h = q * 4;
                const f2 wv0 = {W2[h], W2[h + 1]};
                const f2 wv1 = {W2[h + 2], W2[h + 3]};
                f2 p00 = (f2){q0.x, q0.y} + r2[(h >> 1) + 0];
                f2 p01 = (f2){q0.z, q0.w} + r2[(h >> 1) + 1];
                f2 p10 = (f2){q1.x, q1.y} + r2[(h >> 1) + 0];
                f2 p11 = (f2){q1.z, q1.w} + r2[(h >> 1) + 1];
                p00 = __builtin_elementwise_max(p00, z2);
                p01 = __builtin_elementwise_max(p01, z2);
                p10 = __builtin_elementwise_max(p10, z2);
                p11 = __builtin_elementwise_max(p11, z2);
                acc0 = __builtin_elementwise_fma(p00, wv0, acc0);
                acc0 = __builtin_elementwise_fma(p01, wv1, acc0);
                acc1 = __builtin_elementwise_fma(p10, wv0, acc1);
                acc1 = __builtin_elementwise_fma(p11, wv1, acc1);
            }
            outb[(size_t)(ii + 0) * L_] = acc0.x + acc0.y + pc;   // plain store -> L2
            outb[(size_t)(ii + 1) * L_] = acc1.x + acc1.y + pc;
        }
    } else {
        for (int ii = 0; ii < 8; ++ii) {
            const int i   = i0 + w * 8 + ii;
            const int d   = i - j;
            const int dt  = d < 0 ? 0 : (d > TAU_ ? TAU_ : d);
            const f2* eL  = (const f2*)&ae_lds[dt * AEP_];   // 8B aligned
            const float4* ar = (const float4*)&aiW[ii * H_];
            f2 acc = z2;
#pragma unroll
            for (int q = 0; q < 8; ++q) {
                const float4 qa = ar[q];
                const int h = q * 4;
                const f2 wv0 = {W2[h], W2[h + 1]};
                const f2 wv1 = {W2[h + 2], W2[h + 3]};
                f2 p0 = (f2){qa.x, qa.y} + r2[(h >> 1) + 0] + eL[(h >> 1) + 0];
                f2 p1 = (f2){qa.z, qa.w} + r2[(h >> 1) + 1] + eL[(h >> 1) + 1];
                p0 = __builtin_elementwise_max(p0, z2);
                p1 = __builtin_elementwise_max(p1, z2);
                acc = __builtin_elementwise_fma(p0, wv0, acc);
                acc = __builtin_elementwise_fma(p1, wv1, acc);
            }
            outb[(size_t)ii * L_] = acc.x + acc.y + b2 - 0.2f * (float)dt;  // plain
        }
    }
}

extern "C" void kernel_launch(void* const* d_in, const int* in_sizes, int n_in,
                              void* d_out, int out_size, void* d_ws, size_t ws_size,
                              hipStream_t stream) {
    const float* x   = (const float*)d_in[0];
    const float* dtt = (const float*)d_in[1];
    const float* W1  = (const float*)d_in[2];
    const float* b1  = (const float*)d_in[3];
    const float* W2  = (const float*)d_in[4];
    const float* b2  = (const float*)d_in[5];
    float* out = (float*)d_out;

    float* ws = (float*)d_ws;
    float* ai = ws;                          // B*L*H floats
    float* aj = ws + B_ * L_ * H_;           // B*L*H floats
    float* ae = ws + 2 * B_ * L_ * H_;       // 65*H floats

    const int total  = B_ * L_ * H_ + (TAU_ + 1) * H_;
    const int blocks = (total + 255) / 256;
    hipLaunchKernelGGL(precompute_kernel, dim3(blocks), dim3(256), 0, stream,
                       x, dtt, W1, b1, ai, aj, ae);

    dim3 grid(L_ / 64, L_ / TI_, B_);
    hipLaunchKernelGGL(bias_kernel, grid, dim3(256), 0, stream,
                       ai, aj, ae, W2, b2, out);
}